// Round 10
// baseline (384.085 us; speedup 1.0000x reference)
//
#include <hip/hip_runtime.h>
#include <hip/hip_bf16.h>
#include <stdint.h>

#define BATCH 8
#define SEQ 2048
#define DMODEL 1024

typedef __attribute__((ext_vector_type(4))) float f32x4;
typedef __attribute__((ext_vector_type(8))) short bf16x8;
typedef __attribute__((ext_vector_type(4))) uint32_t u32x4;
typedef __attribute__((ext_vector_type(2))) uint32_t u32x2;

#define MFMA16(a, b, c) __builtin_amdgcn_mfma_f32_16x16x32_bf16((a), (b), (c), 0, 0, 0)

// ---------------------------------------------------------------------------
// PK ("panel-k-major") operand layout for ALL bf16 GEMM operands:
//   elem(r,k) at offset (r>>4)*(Kd*16) + (k>>3)*128 + (r&15)*8 + (k&7)
//  * staging is contiguous + lane-linear in LDS (global_load_lds-legal);
//  * fragment ds_read_b128 is lane-linear -> zero bank conflicts.
// ---------------------------------------------------------------------------

static __device__ __forceinline__ uint16_t f2bf(float f) {
    uint32_t u = __builtin_bit_cast(uint32_t, f);
    u += 0x7fffu + ((u >> 16) & 1u);   // round-to-nearest-even
    return (uint16_t)(u >> 16);
}
static __device__ __forceinline__ uint32_t pk2(float lo, float hi) {
    return (uint32_t)f2bf(lo) | ((uint32_t)f2bf(hi) << 16);
}
// async global->LDS, 16B per lane. LDS dest is wave-uniform base + lane*16.
static __device__ __forceinline__ void gload16(const uint16_t* g, uint16_t* l) {
    __builtin_amdgcn_global_load_lds((const __attribute__((address_space(1))) void*)g,
                                     (__attribute__((address_space(3))) void*)l, 16, 0, 0);
}

// ---------------------------------------------------------------------------
// Kernel 0: f32 row-major -> bf16 PK cast.
// ---------------------------------------------------------------------------
__global__ __launch_bounds__(256) void cast_bf16_pk(const float* __restrict__ src,
                                                    uint16_t* __restrict__ dst) {
    const size_t c = (size_t)blockIdx.x * 256 + threadIdx.x;  // PK chunk id
    const size_t panel = c >> 11;           // 2048 chunks per 16x1024 panel
    const int w = (int)(c & 2047);
    const int ks = w >> 4, r15 = w & 15;
    const float* s = src + (panel * 16 + r15) * DMODEL + ks * 8;
    f32x4 a = *(const f32x4*)s;
    f32x4 b = *(const f32x4*)(s + 4);
    u32x4 o = {pk2(a[0], a[1]), pk2(a[2], a[3]), pk2(b[0], b[1]), pk2(b[2], b[3])};
    *(u32x4*)(dst + c * 8) = o;
}

// ---------------------------------------------------------------------------
// Kernel 1: cast + transpose weights into PK.  WT_pk(n,k) = W[k][n].
// ---------------------------------------------------------------------------
__global__ void wt_cast_kernel(const float* __restrict__ Wk, const float* __restrict__ Wv,
                               const float* __restrict__ Wq, uint16_t* __restrict__ WT) {
    const float* W = blockIdx.z == 0 ? Wk : (blockIdx.z == 1 ? Wv : Wq);
    uint16_t* dst = WT + (size_t)blockIdx.z * DMODEL * DMODEL;
    __shared__ float tile[32][33];
    const int x = blockIdx.x * 32, y = blockIdx.y * 32;
    const int tx = threadIdx.x, ty = threadIdx.y;
#pragma unroll
    for (int j = 0; j < 4; j++)
        tile[ty * 4 + j][tx] = W[(size_t)(y + ty * 4 + j) * DMODEL + x + tx];
    __syncthreads();
#pragma unroll
    for (int j = 0; j < 4; j++) {
        const int n = x + ty * 4 + j, k = y + tx;
        const size_t off = ((size_t)(n >> 4) * (DMODEL / 8) + (k >> 3)) * 128 +
                           (n & 15) * 8 + (k & 7);
        dst[off] = f2bf(tile[tx][ty * 4 + j]);
    }
}

// ---------------------------------------------------------------------------
// Kernel 2: 128x128 pipelined B^T GEMM, BK=64, 4 waves (2M x 2N), 64 KB LDS
// -> 2 BLOCKS/CU (cross-block stall covering, m114) + counted-vmcnt pipeline.
//   C[b][m][n] = sum_k A[b][m][k] * Bt[b][n][k]
// Iteration J computes tiles 2J (slot 0) and 2J+1 (slot 1), 4 phases:
//   ph1 = tile 2J  rows 0-1 (+READ_B slot0) | stage A(2J+1)->As[1]
//   ph2 = tile 2J  rows 2-3                 | stage B(2J+2)->Bs[0] | vmcnt(4)
//   ph3 = tile 2J+1 rows 0-1 (+READ_B slot1)| stage A(2J+2)->As[0]
//   ph4 = tile 2J+1 rows 2-3                | stage B(2J+3)->Bs[1] | vmcnt(4)
// Waits protect the NEXT phase's ds_reads (placed before the barrier the
// reads follow): ph2's vmcnt(4) drains through A(2J+1) (read at ph3),
// ph4's drains through A(2J+2) (read at ph1 of J+1).  Slot reuse is always
// barrier-separated from the last read.  Prologue {B0,A0,B1} + vmcnt(4);
// final iteration peeled with vmcnt(0) at ph2.  16 MFMA per phase, setprio.
// MODE 0: bf16 C in PK * scale. MODE 1: bf16 VT store (PK over [e][s]).
// MODE 2: f32 plain C * Linv[row].   BX=1: batch on blockIdx.x (XCD=batch).
// ---------------------------------------------------------------------------
#define STG_A(kt, sl)                                                         \
    do {                                                                      \
        const size_t k0_ = (size_t)(kt) * 1024;                               \
        gload16(Ab + k0_ + sbA,            &As[sl][tid * 8]);                 \
        gload16(Ab + k0_ + sbA + 2 * eldA, &As[sl][tid * 8 + 2048]);          \
        gload16(Ab + k0_ + sbA + 4 * eldA, &As[sl][tid * 8 + 4096]);          \
        gload16(Ab + k0_ + sbA + 6 * eldA, &As[sl][tid * 8 + 6144]);          \
    } while (0)
#define STG_B(kt, sl)                                                         \
    do {                                                                      \
        const size_t k0_ = (size_t)(kt) * 1024;                               \
        gload16(Bb + k0_ + sbB,            &Bs[sl][tid * 8]);                 \
        gload16(Bb + k0_ + sbB + 2 * eldB, &Bs[sl][tid * 8 + 2048]);          \
        gload16(Bb + k0_ + sbB + 4 * eldB, &Bs[sl][tid * 8 + 4096]);          \
        gload16(Bb + k0_ + sbB + 6 * eldB, &Bs[sl][tid * 8 + 6144]);          \
    } while (0)

#define READ_B(sl)                                                            \
    _Pragma("unroll") for (int j = 0; j < 4; j++) {                           \
        bfr[j][0] = *(const bf16x8*)&Bs[sl][(wc * 4 + j) * 1024 + lbase];     \
        bfr[j][1] = *(const bf16x8*)&Bs[sl][(wc * 4 + j) * 1024 + 512 + lbase]; \
    }

#define VMW4 asm volatile("s_waitcnt vmcnt(4)" ::: "memory")
#define VMW0 asm volatile("s_waitcnt vmcnt(0)" ::: "memory")
#define NOW (void)0
#define NOST (void)0

#define PH_CORE(r0, r1)                                                       \
    __builtin_amdgcn_s_barrier();                                             \
    asm volatile("s_waitcnt lgkmcnt(0)" ::: "memory");                        \
    __builtin_amdgcn_sched_barrier(0);                                        \
    __builtin_amdgcn_s_setprio(1);                                            \
    _Pragma("unroll") for (int j = 0; j < 4; j++) {                           \
        acc[r0][j] = MFMA16(a00, bfr[j][0], acc[r0][j]);                      \
        acc[r0][j] = MFMA16(a01, bfr[j][1], acc[r0][j]);                      \
        acc[r1][j] = MFMA16(a10, bfr[j][0], acc[r1][j]);                      \
        acc[r1][j] = MFMA16(a11, bfr[j][1], acc[r1][j]);                      \
    }                                                                         \
    __builtin_amdgcn_s_setprio(0);                                            \
    __builtin_amdgcn_s_barrier();

#define PH0(sl, STG, WAIT)                                                    \
    do {                                                                      \
        READ_B(sl);                                                           \
        const int ab_ = (wr * 4) * 1024 + lbase;                              \
        bf16x8 a00 = *(const bf16x8*)&As[sl][ab_];                            \
        bf16x8 a01 = *(const bf16x8*)&As[sl][ab_ + 512];                      \
        bf16x8 a10 = *(const bf16x8*)&As[sl][ab_ + 1024];                     \
        bf16x8 a11 = *(const bf16x8*)&As[sl][ab_ + 1536];                     \
        STG;                                                                  \
        WAIT;                                                                 \
        PH_CORE(0, 1)                                                         \
    } while (0)

#define PH1(sl, STG, WAIT)                                                    \
    do {                                                                      \
        const int ab_ = (wr * 4 + 2) * 1024 + lbase;                          \
        bf16x8 a00 = *(const bf16x8*)&As[sl][ab_];                            \
        bf16x8 a01 = *(const bf16x8*)&As[sl][ab_ + 512];                      \
        bf16x8 a10 = *(const bf16x8*)&As[sl][ab_ + 1024];                     \
        bf16x8 a11 = *(const bf16x8*)&As[sl][ab_ + 1536];                     \
        STG;                                                                  \
        WAIT;                                                                 \
        PH_CORE(2, 3)                                                         \
    } while (0)

template <int MODE, int BX>
__global__ __launch_bounds__(256, 2) void gemm128(const uint16_t* __restrict__ Ag,
                                                  const uint16_t* __restrict__ Bg,
                                                  void* __restrict__ Cg,
                                                  const float* __restrict__ Linv,
                                                  float scale, int lda, int ldb, int ldc,
                                                  int nk, size_t sA, size_t sB, size_t sC) {
    __shared__ __align__(16) uint16_t As[2][8192];   // 2 x 16 KB
    __shared__ __align__(16) uint16_t Bs[2][8192];   // 2 x 16 KB  (64 KB total)
    const int bz = BX ? blockIdx.x : blockIdx.z;
    const int bm = BX ? blockIdx.y : blockIdx.x;
    const int bn = BX ? blockIdx.z : blockIdx.y;
    const int m0 = bm * 128, n0 = bn * 128;
    const uint16_t* Ab = Ag + (size_t)bz * sA + (size_t)m0 * lda;  // PK panel base
    const uint16_t* Bb = Bg + (size_t)bz * sB + (size_t)n0 * ldb;
    const int tid = threadIdx.x, lane = tid & 63;
    const int wid = tid >> 6, wr = wid >> 1, wc = wid & 1;
    const int lr = lane & 15, lg = lane >> 4;
    const int lbase = lg * 128 + lr * 8;
    const size_t eldA = (size_t)lda * 16, eldB = (size_t)ldb * 16;
    // staging: chunk c = tid + 256*m -> 16-row panel (tid>>7)+2m, 16B slot tid&127
    const size_t sbA = (size_t)(tid >> 7) * eldA + (tid & 127) * 8;
    const size_t sbB = (size_t)(tid >> 7) * eldB + (tid & 127) * 8;

    f32x4 acc[4][4] = {};
    bf16x8 bfr[4][2];
    // prologue: B0, A0, B1 staged (12 loads); vmcnt(4) keeps B1 in flight.
    STG_B(0, 0);
    STG_A(0, 0);
    STG_B(1, 1);
    VMW4;
    __builtin_amdgcn_s_barrier();
    for (int J = 0; J < nk / 2 - 1; ++J) {
        const int t2 = 2 * J;
        PH0(0, STG_A(t2 + 1, 1), NOW);
        PH1(0, STG_B(t2 + 2, 0), VMW4);
        PH0(1, STG_A(t2 + 2, 0), NOW);
        PH1(1, STG_B(t2 + 3, 1), VMW4);
    }
    // peeled final iteration: tiles nk-2 (slot 0), nk-1 (slot 1)
    PH0(0, STG_A(nk - 1, 1), NOW);
    PH1(0, NOST, VMW0);
    PH0(1, NOST, NOW);
    PH1(1, NOST, NOW);

    if constexpr (MODE == 0) {
        uint16_t* C = (uint16_t*)Cg + (size_t)bz * sC;
#pragma unroll
        for (int i = 0; i < 4; i++) {
            const int gm = m0 + wr * 64 + i * 16 + lg * 4;   // gm&15 == lg*4
            const size_t pbase = (size_t)(gm >> 4) * (ldc / 8);
#pragma unroll
            for (int j = 0; j < 4; j++) {
                const int gn = n0 + wc * 64 + j * 16 + lr;
                const size_t off = (pbase + (gn >> 3)) * 128 + (gn & 7);
#pragma unroll
                for (int r = 0; r < 4; r++)
                    C[off + (lg * 4 + r) * 8] = f2bf(acc[i][j][r] * scale);
            }
        }
    } else if constexpr (MODE == 1) {
        uint16_t* C = (uint16_t*)Cg;
#pragma unroll
        for (int i = 0; i < 4; i++) {
            const int gm = m0 + wr * 64 + i * 16 + lg * 4;   // global m = b*SEQ + s
            const int bb = gm / SEQ;                         // uniform per block
            const int s0 = gm - bb * SEQ;                    // s0&7 in {0,4}
            uint16_t* Cb = C + (size_t)bb * DMODEL * SEQ;
#pragma unroll
            for (int j = 0; j < 4; j++) {
                const int e = n0 + wc * 64 + j * 16 + lr;
                const size_t off = ((size_t)(e >> 4) * (SEQ / 8) + (s0 >> 3)) * 128 +
                                   (e & 15) * 8 + (s0 & 7);
                u32x2 v = {pk2(acc[i][j][0], acc[i][j][1]), pk2(acc[i][j][2], acc[i][j][3])};
                *(u32x2*)&Cb[off] = v;
            }
        }
    } else {
        float* C = (float*)Cg + (size_t)bz * sC;
        const float* LB = Linv + bz * SEQ;
#pragma unroll
        for (int i = 0; i < 4; i++) {
            const int gm = m0 + wr * 64 + i * 16 + lg * 4;
            const f32x4 lv = *(const f32x4*)&LB[gm];
#pragma unroll
            for (int j = 0; j < 4; j++) {
                const int gn = n0 + wc * 64 + j * 16 + lr;
#pragma unroll
                for (int r = 0; r < 4; r++)
                    C[(size_t)(gm + r) * ldc + gn] = acc[i][j][r] * lv[r];
            }
        }
    }
}

// ---------------------------------------------------------------------------
// Kernel 3: row softmax on PK-layout S, in place.  One block per 16-row panel
// (contiguous 32KB).  Thread t owns row t&15, k-slots (t>>4)+16u, u=0..15.
// ---------------------------------------------------------------------------
__global__ __launch_bounds__(256) void softmax_pk(uint16_t* __restrict__ S,
                                                  float* __restrict__ Linv) {
    const size_t panel = blockIdx.x;
    uint16_t* sp = S + panel * (size_t)(16 * SEQ);
    const int t = threadIdx.x, lane = t & 63, w = t >> 6;
    const int r15 = t & 15, ksl = t >> 4;
    __shared__ float rm[4][16], rs[4][16];
    u32x4 raw[16];
    float mx = -3.0e38f;
#pragma unroll
    for (int u = 0; u < 16; u++) {
        raw[u] = *(const u32x4*)&sp[(ksl + u * 16) * 128 + r15 * 8];
#pragma unroll
        for (int j = 0; j < 4; j++) {
            mx = fmaxf(mx, __builtin_bit_cast(float, raw[u][j] << 16));
            mx = fmaxf(mx, __builtin_bit_cast(float, raw[u][j] & 0xffff0000u));
        }
    }
    mx = fmaxf(mx, __shfl_xor(mx, 16));
    mx = fmaxf(mx, __shfl_xor(mx, 32));
    if (lane < 16) rm[w][lane] = mx;
    __syncthreads();
    const float m = fmaxf(fmaxf(rm[0][r15], rm[1][r15]), fmaxf(rm[2][r15], rm[3][r15]));
    float sum = 0.0f;
#pragma unroll
    for (int u = 0; u < 16; u++) {
#pragma unroll
        for (int j = 0; j < 4; j++) {
            float lo = __expf(__builtin_bit_cast(float, raw[u][j] << 16) - m);
            float hi = __expf(__builtin_bit_cast(float, raw[u][j] & 0xffff0000u) - m);
            sum += lo + hi;
            raw[u][j] = pk2(lo, hi);
        }
    }
    sum += __shfl_xor(sum, 16);
    sum += __shfl_xor(sum, 32);
    if (lane < 16) rs[w][lane] = sum;
    __syncthreads();
    const float tot = rs[0][r15] + rs[1][r15] + rs[2][r15] + rs[3][r15];
#pragma unroll
    for (int u = 0; u < 16; u++)
        *(u32x4*)&sp[(ksl + u * 16) * 128 + r15 * 8] = raw[u];
    if (w == 0 && lane < 16) Linv[panel * 16 + lane] = 1.0f / tot;
}

// ---------------------------------------------------------------------------
// Workspace layout (bytes), all bf16 matrices in PK layout:
//   Qbf [16384][1024] :          0   (Q pre-scaled by 1/32)
//   Kbf [16384][1024] :  33,554,432
//   VTb [8][1024][2048]: 67,108,864
//   WT  [3][1024][1024]:100,663,296
//   Linv[16384] f32   : 106,954,752
//   S/P [8][2048][2048]:107,020,288  (P in place)
//   Xbf [16384][1024] :171,966,464  (reused for Xq, Xk, Xv in turn)
// ---------------------------------------------------------------------------
extern "C" void kernel_launch(void* const* d_in, const int* in_sizes, int n_in,
                              void* d_out, int out_size, void* d_ws, size_t ws_size,
                              hipStream_t stream) {
    const float* Xk = (const float*)d_in[0];
    const float* Xv = (const float*)d_in[1];
    const float* Xq = (const float*)d_in[2];
    const float* Wk = (const float*)d_in[3];
    const float* Wv = (const float*)d_in[4];
    const float* Wq = (const float*)d_in[5];
    float* out = (float*)d_out;
    char* ws = (char*)d_ws;
    uint16_t* Qbf = (uint16_t*)(ws);
    uint16_t* Kbf = (uint16_t*)(ws + (size_t)33554432);
    uint16_t* VTb = (uint16_t*)(ws + (size_t)67108864);
    uint16_t* WT  = (uint16_t*)(ws + (size_t)100663296);
    float*    Linv= (float*)(ws + (size_t)106954752);
    uint16_t* Sb  = (uint16_t*)(ws + (size_t)107020288);
    uint16_t* Xbf = (uint16_t*)(ws + (size_t)171966464);

    wt_cast_kernel<<<dim3(32, 32, 3), dim3(32, 8), 0, stream>>>(Wk, Wv, Wq, WT);
    // Q projection (scale 1/sqrt(1024) folded into bf16 store)
    cast_bf16_pk<<<8192, 256, 0, stream>>>(Xq, Xbf);
    gemm128<0, 0><<<dim3(128, 8, 1), 256, 0, stream>>>(
        Xbf, WT + 2 * 1048576, (void*)Qbf, nullptr, 0.03125f,
        DMODEL, DMODEL, DMODEL, DMODEL / 64, 0, 0, 0);
    // K projection
    cast_bf16_pk<<<8192, 256, 0, stream>>>(Xk, Xbf);
    gemm128<0, 0><<<dim3(128, 8, 1), 256, 0, stream>>>(
        Xbf, WT, (void*)Kbf, nullptr, 1.0f,
        DMODEL, DMODEL, DMODEL, DMODEL / 64, 0, 0, 0);
    // V projection with transposed store -> VT PK over [e][s]
    cast_bf16_pk<<<8192, 256, 0, stream>>>(Xv, Xbf);
    gemm128<1, 0><<<dim3(128, 8, 1), 256, 0, stream>>>(
        Xbf, WT + 1048576, (void*)VTb, nullptr, 1.0f,
        DMODEL, DMODEL, 0, DMODEL / 64, 0, 0, 0);
    // scores: S[b][q][k] = Qhat[b] . K[b]^T  (bf16 PK store), XCD = batch
    gemm128<0, 1><<<dim3(8, 16, 16), 256, 0, stream>>>(
        Qbf, Kbf, (void*)Sb, nullptr, 1.0f,
        DMODEL, DMODEL, SEQ, DMODEL / 64,
        (size_t)SEQ * DMODEL, (size_t)SEQ * DMODEL, (size_t)SEQ * SEQ);
    // in-place row softmax -> P, Linv
    softmax_pk<<<dim3(BATCH * SEQ / 16), 256, 0, stream>>>(Sb, Linv);
    // Z[b][q][e] = (P[b] . V[b]) * Linv  (f32 plain store)
    gemm128<2, 1><<<dim3(8, 16, 8), 256, 0, stream>>>(
        Sb, VTb, (void*)out, Linv, 1.0f,
        SEQ, SEQ, DMODEL, SEQ / 64,
        (size_t)SEQ * SEQ, (size_t)DMODEL * SEQ, (size_t)SEQ * DMODEL);
}

// Round 12
// 343.092 us; speedup vs baseline: 1.1195x; 1.1195x over previous
//
#include <hip/hip_runtime.h>
#include <hip/hip_bf16.h>
#include <stdint.h>

#define BATCH 8
#define SEQ 2048
#define DMODEL 1024

typedef __attribute__((ext_vector_type(4))) float f32x4;
typedef __attribute__((ext_vector_type(8))) short bf16x8;
typedef __attribute__((ext_vector_type(4))) uint32_t u32x4;
typedef __attribute__((ext_vector_type(2))) uint32_t u32x2;

#define MFMA16(a, b, c) __builtin_amdgcn_mfma_f32_16x16x32_bf16((a), (b), (c), 0, 0, 0)

// ---------------------------------------------------------------------------
// PK ("panel-k-major") operand layout for ALL bf16 GEMM operands:
//   elem(r,k) at offset (r>>4)*(Kd*16) + (k>>3)*128 + (r&15)*8 + (k&7)
//  * staging is contiguous + lane-linear in LDS (global_load_lds-legal);
//  * fragment ds_read_b128 is lane-linear -> zero bank conflicts.
// ---------------------------------------------------------------------------

static __device__ __forceinline__ uint16_t f2bf(float f) {
    uint32_t u = __builtin_bit_cast(uint32_t, f);
    u += 0x7fffu + ((u >> 16) & 1u);   // round-to-nearest-even
    return (uint16_t)(u >> 16);
}
static __device__ __forceinline__ uint32_t pk2(float lo, float hi) {
    return (uint32_t)f2bf(lo) | ((uint32_t)f2bf(hi) << 16);
}
// async global->LDS, 16B per lane. LDS dest is wave-uniform base + lane*16.
static __device__ __forceinline__ void gload16(const uint16_t* g, uint16_t* l) {
    __builtin_amdgcn_global_load_lds((const __attribute__((address_space(1))) void*)g,
                                     (__attribute__((address_space(3))) void*)l, 16, 0, 0);
}

// ---------------------------------------------------------------------------
// Kernel 0: f32 row-major -> bf16 PK cast, all three X inputs in one dispatch
// (blockIdx.y selects input/output pair).  Destinations MUST be disjoint:
// XqB lives in d_out (dead until final PV store), XkB/XvB in the S region
// (dead until scores writes S).
// ---------------------------------------------------------------------------
__global__ __launch_bounds__(256) void cast3_bf16_pk(const float* __restrict__ x0,
                                                     const float* __restrict__ x1,
                                                     const float* __restrict__ x2,
                                                     uint16_t* __restrict__ d0,
                                                     uint16_t* __restrict__ d1,
                                                     uint16_t* __restrict__ d2) {
    const int z = blockIdx.y;
    const float* src = z == 0 ? x0 : (z == 1 ? x1 : x2);
    uint16_t* dst = z == 0 ? d0 : (z == 1 ? d1 : d2);
    const size_t c = (size_t)blockIdx.x * 256 + threadIdx.x;  // PK chunk id
    const size_t panel = c >> 11;           // 2048 chunks per 16x1024 panel
    const int w = (int)(c & 2047);
    const int ks = w >> 4, r15 = w & 15;
    const float* s = src + (panel * 16 + r15) * DMODEL + ks * 8;
    f32x4 a = *(const f32x4*)s;
    f32x4 b = *(const f32x4*)(s + 4);
    u32x4 o = {pk2(a[0], a[1]), pk2(a[2], a[3]), pk2(b[0], b[1]), pk2(b[2], b[3])};
    *(u32x4*)(dst + c * 8) = o;
}

// ---------------------------------------------------------------------------
// Kernel 1: cast + transpose weights into PK.  WT_pk(n,k) = W[k][n].
// ---------------------------------------------------------------------------
__global__ void wt_cast_kernel(const float* __restrict__ Wk, const float* __restrict__ Wv,
                               const float* __restrict__ Wq, uint16_t* __restrict__ WT) {
    const float* W = blockIdx.z == 0 ? Wk : (blockIdx.z == 1 ? Wv : Wq);
    uint16_t* dst = WT + (size_t)blockIdx.z * DMODEL * DMODEL;
    __shared__ float tile[32][33];
    const int x = blockIdx.x * 32, y = blockIdx.y * 32;
    const int tx = threadIdx.x, ty = threadIdx.y;
#pragma unroll
    for (int j = 0; j < 4; j++)
        tile[ty * 4 + j][tx] = W[(size_t)(y + ty * 4 + j) * DMODEL + x + tx];
    __syncthreads();
#pragma unroll
    for (int j = 0; j < 4; j++) {
        const int n = x + ty * 4 + j, k = y + tx;
        const size_t off = ((size_t)(n >> 4) * (DMODEL / 8) + (k >> 3)) * 128 +
                           (n & 15) * 8 + (k & 7);
        dst[off] = f2bf(tile[tx][ty * 4 + j]);
    }
}

// ---------------------------------------------------------------------------
// Kernel 2: 8-phase pipelined 256x256 B^T GEMM, BK=64, 8 waves (2M x 4N),
// double-buffered 128 KB LDS, PK operands, REDUCED-BARRIER schedule.
//   C[b][m][n] = sum_k A[b][m][k] * Bt[b][n][k]
// Per phase: {4 ds_read_b128 (A quadrant) || stage one 16KB half -> s_barrier
// -> lgkmcnt(0)+sched_barrier -> setprio(1), 16 MFMA, setprio(0)}.
// TRAILING barrier ONLY on phases 4 and 8 (slot-adjacency ledger):
//   stage@ph1/2 -> As[1], last read ph5-8 prev iter: protected by ph8 end-bar
//   stage@ph3/4 -> Bs[0], last read = READ_B(0) (pre-ph1): all waves' reads
//     drained by their lgkm0(ph1), which precedes bar(ph2) in program order;
//     ph3's stage issues after bar(ph2)+bar(ph3-entry) path.  Distance-2: safe.
//   stage@ph5/6 -> As[0], last read ph4: protected by ph4 end-bar.
//   stage@ph7/8 -> Bs[1], last read = READ_B(1) (pre-ph5): drained by
//     lgkm0(ph5) < bar(ph6) < ph7's stage.  Distance-2: safe.
// vmcnt ledger: at ph4's vmcnt(4), outstanding (oldest first) = [B(t+1) prev
// ph7/8 if any, A(t+1) ph1/2, B(t+2) ph3/4] -> wait to 4 leaves only B(t+2):
// A(t+1) AND B(t+1) landed before READ_B(1)/ph5.  Symmetric at ph8.
// MODE 0: bf16 C in PK * scale. MODE 1: bf16 VT store (PK over [e][s]).
// MODE 2: f32 plain C * Linv[row].  MODE 3: merged QKV projection (bz selects
// input/weight/output/epilogue; A bases passed separately — they live in
// different allocations).  BX=1: batch on blockIdx.x (XCD=batch).
// ---------------------------------------------------------------------------
#define STG_A(kt, sl, h)                                                          \
    do {                                                                          \
        const size_t g0 = (size_t)((h) * 8 + (tid >> 7)) * eldA +                 \
                          (size_t)(kt) * 1024 + (tid & 127) * 8;                  \
        gload16(Ab + g0, &As[sl][(h) * 8192 + tid * 8]);                          \
        gload16(Ab + g0 + 4 * eldA, &As[sl][(h) * 8192 + tid * 8 + 4096]);        \
    } while (0)
#define STG_B(kt, sl, h)                                                          \
    do {                                                                          \
        const size_t g0 = (size_t)((h) * 8 + (tid >> 7)) * eldB +                 \
                          (size_t)(kt) * 1024 + (tid & 127) * 8;                  \
        gload16(Bb + g0, &Bs[sl][(h) * 8192 + tid * 8]);                          \
        gload16(Bb + g0 + 4 * eldB, &Bs[sl][(h) * 8192 + tid * 8 + 4096]);        \
    } while (0)

#define READ_B(sl)                                                                \
    _Pragma("unroll") for (int j = 0; j < 4; j++) {                               \
        bfr[j][0] = *(const bf16x8*)&Bs[sl][(wc * 4 + j) * 1024 + lbase];         \
        bfr[j][1] = *(const bf16x8*)&Bs[sl][(wc * 4 + j) * 1024 + 512 + lbase];   \
    }

#define VM4 asm volatile("s_waitcnt vmcnt(4)" ::: "memory")
#define VM0 asm volatile("s_waitcnt vmcnt(0)" ::: "memory")
#define NOPW (void)0
#define NOST (void)0
#define ENDBAR __builtin_amdgcn_s_barrier()
#define NOB (void)0

#define PH(sl, q, STG, WAIT, EB)                                                  \
    do {                                                                          \
        const int ab = (wr * 8 + 2 * (q)) * 1024 + lbase;                         \
        bf16x8 a00 = *(const bf16x8*)&As[sl][ab];                                 \
        bf16x8 a01 = *(const bf16x8*)&As[sl][ab + 512];                           \
        bf16x8 a10 = *(const bf16x8*)&As[sl][ab + 1024];                          \
        bf16x8 a11 = *(const bf16x8*)&As[sl][ab + 1536];                          \
        STG;                                                                      \
        WAIT;                                                                     \
        __builtin_amdgcn_s_barrier();                                             \
        asm volatile("s_waitcnt lgkmcnt(0)" ::: "memory");                        \
        __builtin_amdgcn_sched_barrier(0);                                        \
        __builtin_amdgcn_s_setprio(1);                                            \
        _Pragma("unroll") for (int j = 0; j < 4; j++) {                           \
            acc[2 * (q)][j] = MFMA16(a00, bfr[j][0], acc[2 * (q)][j]);            \
            acc[2 * (q)][j] = MFMA16(a01, bfr[j][1], acc[2 * (q)][j]);            \
            acc[2 * (q) + 1][j] = MFMA16(a10, bfr[j][0], acc[2 * (q) + 1][j]);    \
            acc[2 * (q) + 1][j] = MFMA16(a11, bfr[j][1], acc[2 * (q) + 1][j]);    \
        }                                                                         \
        __builtin_amdgcn_s_setprio(0);                                            \
        EB;                                                                       \
    } while (0)

template <int MODE, int BX>
__global__ __launch_bounds__(512, 2) void gemm8p(const uint16_t* __restrict__ Ag,
                                                 const uint16_t* __restrict__ Bg,
                                                 void* __restrict__ Cg,
                                                 const float* __restrict__ Linv,
                                                 float scale, int lda, int ldb, int ldc,
                                                 int nk, size_t sA, size_t sB, size_t sC,
                                                 const uint16_t* __restrict__ A2,
                                                 const uint16_t* __restrict__ A3,
                                                 void* __restrict__ C2,
                                                 void* __restrict__ C3) {
    __shared__ __align__(16) uint16_t As[2][16384];   // 64 KB
    __shared__ __align__(16) uint16_t Bs[2][16384];   // 64 KB
    const int bz = BX ? blockIdx.x : blockIdx.z;
    const int bm = BX ? blockIdx.y : blockIdx.x;
    const int bn = BX ? blockIdx.z : blockIdx.y;
    const int m0 = bm * 256, n0 = bn * 256;
    const uint16_t *Abase, *Bbase;
    if constexpr (MODE == 3) {
        // merged projection: bz = 0(Q) / 1(K) / 2(V); WT order in memory: K,V,Q
        Abase = (bz == 0) ? Ag : (bz == 1) ? A2 : A3;
        Bbase = Bg + ((bz == 0) ? 2 * sB : (bz == 1) ? (size_t)0 : sB);
    } else {
        Abase = Ag + (size_t)bz * sA;
        Bbase = Bg + (size_t)bz * sB;
    }
    const uint16_t* Ab = Abase + (size_t)m0 * lda;  // PK panel base
    const uint16_t* Bb = Bbase + (size_t)n0 * ldb;
    const int tid = threadIdx.x, lane = tid & 63;
    const int wid = tid >> 6, wr = wid >> 2, wc = wid & 3;
    const int lr = lane & 15, lg = lane >> 4;
    const int lbase = lg * 128 + lr * 8;
    const size_t eldA = (size_t)lda * 16, eldB = (size_t)ldb * 16;

    f32x4 acc[8][4] = {};
    bf16x8 bfr[4][2];
    // prologue: tile0 (A0,A1,B0,B1) + tile1 (B0,B1); vmcnt(4) keeps tile1's
    // B-halves in flight, tile0 landed.
    STG_A(0, 0, 0); STG_A(0, 0, 1);
    STG_B(0, 0, 0); STG_B(0, 0, 1);
    STG_B(1, 1, 0); STG_B(1, 1, 1);
    VM4;
    __builtin_amdgcn_s_barrier();
    for (int kt = 0; kt + 3 < nk; kt += 2) {
        READ_B(0);
        PH(0, 0, STG_A(kt + 1, 1, 0), NOPW, NOB);
        PH(0, 1, STG_A(kt + 1, 1, 1), NOPW, NOB);
        PH(0, 2, STG_B(kt + 2, 0, 0), NOPW, NOB);
        PH(0, 3, STG_B(kt + 2, 0, 1), VM4, ENDBAR);
        READ_B(1);
        PH(1, 0, STG_A(kt + 2, 0, 0), NOPW, NOB);
        PH(1, 1, STG_A(kt + 2, 0, 1), NOPW, NOB);
        PH(1, 2, STG_B(kt + 3, 1, 0), NOPW, NOB);
        PH(1, 3, STG_B(kt + 3, 1, 1), VM4, ENDBAR);
    }
    // epilogue iteration: tiles nk-2, nk-1 (no staging beyond nk-1)
    READ_B(0);
    PH(0, 0, STG_A(nk - 1, 1, 0), NOPW, NOB);
    PH(0, 1, STG_A(nk - 1, 1, 1), NOPW, NOB);
    PH(0, 2, NOST, NOPW, NOB);
    PH(0, 3, NOST, VM0, ENDBAR);
    READ_B(1);
    PH(1, 0, NOST, NOPW, NOB);
    PH(1, 1, NOST, NOPW, NOB);
    PH(1, 2, NOST, NOPW, NOB);
    PH(1, 3, NOST, NOPW, NOB);

    if constexpr (MODE == 0) {
        uint16_t* C = (uint16_t*)Cg + (size_t)bz * sC;
#pragma unroll
        for (int i = 0; i < 8; i++) {
            const int gm = m0 + wr * 128 + i * 16 + lg * 4;   // gm&15 == lg*4
            const size_t pbase = (size_t)(gm >> 4) * (ldc / 8);
#pragma unroll
            for (int j = 0; j < 4; j++) {
                const int gn = n0 + wc * 64 + j * 16 + lr;
                const size_t off = (pbase + (gn >> 3)) * 128 + (gn & 7);
#pragma unroll
                for (int r = 0; r < 4; r++)
                    C[off + (lg * 4 + r) * 8] = f2bf(acc[i][j][r] * scale);
            }
        }
    } else if constexpr (MODE == 1) {
        uint16_t* C = (uint16_t*)Cg;
#pragma unroll
        for (int i = 0; i < 8; i++) {
            const int gm = m0 + wr * 128 + i * 16 + lg * 4;  // global m = b*SEQ + s
            const int bb = gm / SEQ;                         // uniform per block
            const int s0 = gm - bb * SEQ;                    // s0&7 in {0,4}
            uint16_t* Cb = C + (size_t)bb * DMODEL * SEQ;
#pragma unroll
            for (int j = 0; j < 4; j++) {
                const int e = n0 + wc * 64 + j * 16 + lr;
                const size_t off = ((size_t)(e >> 4) * (SEQ / 8) + (s0 >> 3)) * 128 +
                                   (e & 15) * 8 + (s0 & 7);
                u32x2 v = {pk2(acc[i][j][0], acc[i][j][1]), pk2(acc[i][j][2], acc[i][j][3])};
                *(u32x2*)&Cb[off] = v;
            }
        }
    } else if constexpr (MODE == 2) {
        float* C = (float*)Cg + (size_t)bz * sC;
        const float* LB = Linv + bz * SEQ;
#pragma unroll
        for (int i = 0; i < 8; i++) {
            const int gm = m0 + wr * 128 + i * 16 + lg * 4;
            const f32x4 lv = *(const f32x4*)&LB[gm];
#pragma unroll
            for (int j = 0; j < 4; j++) {
                const int gn = n0 + wc * 64 + j * 16 + lr;
#pragma unroll
                for (int r = 0; r < 4; r++)
                    C[(size_t)(gm + r) * ldc + gn] = acc[i][j][r] * lv[r];
            }
        }
    } else {  // MODE 3: merged projection epilogue
        if (bz < 2) {
            uint16_t* C = (uint16_t*)(bz == 0 ? Cg : C2);
            const float sc = bz == 0 ? scale : 1.0f;
#pragma unroll
            for (int i = 0; i < 8; i++) {
                const int gm = m0 + wr * 128 + i * 16 + lg * 4;
                const size_t pbase = (size_t)(gm >> 4) * (ldc / 8);
#pragma unroll
                for (int j = 0; j < 4; j++) {
                    const int gn = n0 + wc * 64 + j * 16 + lr;
                    const size_t off = (pbase + (gn >> 3)) * 128 + (gn & 7);
#pragma unroll
                    for (int r = 0; r < 4; r++)
                        C[off + (lg * 4 + r) * 8] = f2bf(acc[i][j][r] * sc);
                }
            }
        } else {
            uint16_t* C = (uint16_t*)C3;
#pragma unroll
            for (int i = 0; i < 8; i++) {
                const int gm = m0 + wr * 128 + i * 16 + lg * 4;
                const int bb = gm / SEQ;
                const int s0 = gm - bb * SEQ;
                uint16_t* Cb = C + (size_t)bb * DMODEL * SEQ;
#pragma unroll
                for (int j = 0; j < 4; j++) {
                    const int e = n0 + wc * 64 + j * 16 + lr;
                    const size_t off = ((size_t)(e >> 4) * (SEQ / 8) + (s0 >> 3)) * 128 +
                                       (e & 15) * 8 + (s0 & 7);
                    u32x2 v = {pk2(acc[i][j][0], acc[i][j][1]),
                               pk2(acc[i][j][2], acc[i][j][3])};
                    *(u32x2*)&Cb[off] = v;
                }
            }
        }
    }
}

// ---------------------------------------------------------------------------
// Kernel 3: row softmax on PK-layout S, in place.  One block per 16-row panel
// (contiguous 32KB).  Thread t owns row t&15, k-slots (t>>4)+16u, u=0..15.
// ---------------------------------------------------------------------------
__global__ __launch_bounds__(256) void softmax_pk(uint16_t* __restrict__ S,
                                                  float* __restrict__ Linv) {
    const size_t panel = blockIdx.x;
    uint16_t* sp = S + panel * (size_t)(16 * SEQ);
    const int t = threadIdx.x, lane = t & 63, w = t >> 6;
    const int r15 = t & 15, ksl = t >> 4;
    __shared__ float rm[4][16], rs[4][16];
    u32x4 raw[16];
    float mx = -3.0e38f;
#pragma unroll
    for (int u = 0; u < 16; u++) {
        raw[u] = *(const u32x4*)&sp[(ksl + u * 16) * 128 + r15 * 8];
#pragma unroll
        for (int j = 0; j < 4; j++) {
            mx = fmaxf(mx, __builtin_bit_cast(float, raw[u][j] << 16));
            mx = fmaxf(mx, __builtin_bit_cast(float, raw[u][j] & 0xffff0000u));
        }
    }
    mx = fmaxf(mx, __shfl_xor(mx, 16));
    mx = fmaxf(mx, __shfl_xor(mx, 32));
    if (lane < 16) rm[w][lane] = mx;
    __syncthreads();
    const float m = fmaxf(fmaxf(rm[0][r15], rm[1][r15]), fmaxf(rm[2][r15], rm[3][r15]));
    float sum = 0.0f;
#pragma unroll
    for (int u = 0; u < 16; u++) {
#pragma unroll
        for (int j = 0; j < 4; j++) {
            float lo = __expf(__builtin_bit_cast(float, raw[u][j] << 16) - m);
            float hi = __expf(__builtin_bit_cast(float, raw[u][j] & 0xffff0000u) - m);
            sum += lo + hi;
            raw[u][j] = pk2(lo, hi);
        }
    }
    sum += __shfl_xor(sum, 16);
    sum += __shfl_xor(sum, 32);
    if (lane < 16) rs[w][lane] = sum;
    __syncthreads();
    const float tot = rs[0][r15] + rs[1][r15] + rs[2][r15] + rs[3][r15];
#pragma unroll
    for (int u = 0; u < 16; u++)
        *(u32x4*)&sp[(ksl + u * 16) * 128 + r15 * 8] = raw[u];
    if (w == 0 && lane < 16) Linv[panel * 16 + lane] = 1.0f / tot;
}

// ---------------------------------------------------------------------------
// Buffer plan (aliasing-audited, r11 bug fixed):
//   ws:  Qbf [0, 33.5M)  Kbf [33.5M, 67.1M)  VTb [67.1M, 100.7M)
//        WT  [100.7M, 106.95M)  Linv [106.95M, ~107M)
//        S/P [107,020,288 .. 174,129,152)
//   X casts (all DISJOINT, all dead before their region is re-written):
//        XqB = d_out[0 .. 32M)            (PV writes all of d_out at the end)
//        XkB = S + 0       [107,020,288)  (scores writes S after proj done)
//        XvB = S + 33.5MB  [140,574,720)
//   Temporal chain: cast3 -> proj(reads X*, writes Q/K/VT) -> scores(clobbers
//   XkB/XvB) -> softmax -> PV(clobbers XqB, writes full out).
// ---------------------------------------------------------------------------
extern "C" void kernel_launch(void* const* d_in, const int* in_sizes, int n_in,
                              void* d_out, int out_size, void* d_ws, size_t ws_size,
                              hipStream_t stream) {
    const float* Xk = (const float*)d_in[0];
    const float* Xv = (const float*)d_in[1];
    const float* Xq = (const float*)d_in[2];
    const float* Wk = (const float*)d_in[3];
    const float* Wv = (const float*)d_in[4];
    const float* Wq = (const float*)d_in[5];
    float* out = (float*)d_out;
    char* ws = (char*)d_ws;
    uint16_t* Qbf = (uint16_t*)(ws);
    uint16_t* Kbf = (uint16_t*)(ws + (size_t)33554432);
    uint16_t* VTb = (uint16_t*)(ws + (size_t)67108864);
    uint16_t* WT  = (uint16_t*)(ws + (size_t)100663296);
    float*    Linv= (float*)(ws + (size_t)106954752);
    uint16_t* Sb  = (uint16_t*)(ws + (size_t)107020288);
    uint16_t* XqB = (uint16_t*)d_out;                        // 32 MB of 64 MB out
    uint16_t* XkB = Sb;                                      // S + 0
    uint16_t* XvB = (uint16_t*)(ws + (size_t)140574720);     // S + 32 MB

    wt_cast_kernel<<<dim3(32, 32, 3), dim3(32, 8), 0, stream>>>(Wk, Wv, Wq, WT);
    // all three input casts in one dispatch (disjoint destinations)
    cast3_bf16_pk<<<dim3(8192, 3), 256, 0, stream>>>(Xq, Xk, Xv, XqB, XkB, XvB);
    // merged Q/K/V projection: z=0 Q (scale 1/32), z=1 K, z=2 V (VT store)
    gemm8p<3, 0><<<dim3(64, 4, 3), 512, 0, stream>>>(
        XqB, WT, (void*)Qbf, nullptr, 0.03125f,
        DMODEL, DMODEL, DMODEL, DMODEL / 64,
        0, (size_t)1048576 /*WT stride*/, 0,
        XkB, XvB, (void*)Kbf, (void*)VTb);
    // scores: S[b][q][k] = Qhat[b] . K[b]^T  (bf16 PK store), XCD = batch
    gemm8p<0, 1><<<dim3(8, 8, 8), 512, 0, stream>>>(
        Qbf, Kbf, (void*)Sb, nullptr, 1.0f,
        DMODEL, DMODEL, SEQ, DMODEL / 64,
        (size_t)SEQ * DMODEL, (size_t)SEQ * DMODEL, (size_t)SEQ * SEQ,
        nullptr, nullptr, nullptr, nullptr);
    // in-place row softmax -> P, Linv
    softmax_pk<<<dim3(BATCH * SEQ / 16), 256, 0, stream>>>(Sb, Linv);
    // Z[b][q][e] = (P[b] . V[b]) * Linv  (f32 plain store)
    gemm8p<2, 1><<<dim3(8, 8, 4), 512, 0, stream>>>(
        Sb, VTb, (void*)out, Linv, 1.0f,
        SEQ, SEQ, DMODEL, SEQ / 64,
        (size_t)SEQ * SEQ, (size_t)DMODEL * SEQ, (size_t)SEQ * DMODEL,
        nullptr, nullptr, nullptr, nullptr);
}

// Round 13
// 342.666 us; speedup vs baseline: 1.1209x; 1.0012x over previous
//
#include <hip/hip_runtime.h>
#include <hip/hip_bf16.h>
#include <stdint.h>

#define BATCH 8
#define SEQ 2048
#define DMODEL 1024

typedef __attribute__((ext_vector_type(4))) float f32x4;
typedef __attribute__((ext_vector_type(8))) short bf16x8;
typedef __attribute__((ext_vector_type(4))) uint32_t u32x4;
typedef __attribute__((ext_vector_type(2))) uint32_t u32x2;

#define MFMA16(a, b, c) __builtin_amdgcn_mfma_f32_16x16x32_bf16((a), (b), (c), 0, 0, 0)

// ---------------------------------------------------------------------------
// PK ("panel-k-major") operand layout for ALL bf16 GEMM operands:
//   elem(r,k) at offset (r>>4)*(Kd*16) + (k>>3)*128 + (r&15)*8 + (k&7)
//  * staging is contiguous + lane-linear in LDS (global_load_lds-legal);
//  * fragment ds_read_b128 is lane-linear -> zero bank conflicts.
// ---------------------------------------------------------------------------

static __device__ __forceinline__ uint16_t f2bf(float f) {
    uint32_t u = __builtin_bit_cast(uint32_t, f);
    u += 0x7fffu + ((u >> 16) & 1u);   // round-to-nearest-even
    return (uint16_t)(u >> 16);
}
static __device__ __forceinline__ uint32_t pk2(float lo, float hi) {
    return (uint32_t)f2bf(lo) | ((uint32_t)f2bf(hi) << 16);
}
// async global->LDS, 16B per lane. LDS dest is wave-uniform base + lane*16.
static __device__ __forceinline__ void gload16(const uint16_t* g, uint16_t* l) {
    __builtin_amdgcn_global_load_lds((const __attribute__((address_space(1))) void*)g,
                                     (__attribute__((address_space(3))) void*)l, 16, 0, 0);
}

// ---------------------------------------------------------------------------
// Kernel 0: f32 row-major -> bf16 PK cast, all three X inputs in one dispatch.
// Destinations are DISJOINT (XqB in d_out, XkB/XvB in the dead S region).
// ---------------------------------------------------------------------------
__global__ __launch_bounds__(256) void cast3_bf16_pk(const float* __restrict__ x0,
                                                     const float* __restrict__ x1,
                                                     const float* __restrict__ x2,
                                                     uint16_t* __restrict__ d0,
                                                     uint16_t* __restrict__ d1,
                                                     uint16_t* __restrict__ d2) {
    const int z = blockIdx.y;
    const float* src = z == 0 ? x0 : (z == 1 ? x1 : x2);
    uint16_t* dst = z == 0 ? d0 : (z == 1 ? d1 : d2);
    const size_t c = (size_t)blockIdx.x * 256 + threadIdx.x;  // PK chunk id
    const size_t panel = c >> 11;           // 2048 chunks per 16x1024 panel
    const int w = (int)(c & 2047);
    const int ks = w >> 4, r15 = w & 15;
    const float* s = src + (panel * 16 + r15) * DMODEL + ks * 8;
    f32x4 a = *(const f32x4*)s;
    f32x4 b = *(const f32x4*)(s + 4);
    u32x4 o = {pk2(a[0], a[1]), pk2(a[2], a[3]), pk2(b[0], b[1]), pk2(b[2], b[3])};
    *(u32x4*)(dst + c * 8) = o;
}

// ---------------------------------------------------------------------------
// Kernel 1: cast + transpose weights into PK.  WT_pk(n,k) = W[k][n].
// ---------------------------------------------------------------------------
__global__ void wt_cast_kernel(const float* __restrict__ Wk, const float* __restrict__ Wv,
                               const float* __restrict__ Wq, uint16_t* __restrict__ WT) {
    const float* W = blockIdx.z == 0 ? Wk : (blockIdx.z == 1 ? Wv : Wq);
    uint16_t* dst = WT + (size_t)blockIdx.z * DMODEL * DMODEL;
    __shared__ float tile[32][33];
    const int x = blockIdx.x * 32, y = blockIdx.y * 32;
    const int tx = threadIdx.x, ty = threadIdx.y;
#pragma unroll
    for (int j = 0; j < 4; j++)
        tile[ty * 4 + j][tx] = W[(size_t)(y + ty * 4 + j) * DMODEL + x + tx];
    __syncthreads();
#pragma unroll
    for (int j = 0; j < 4; j++) {
        const int n = x + ty * 4 + j, k = y + tx;
        const size_t off = ((size_t)(n >> 4) * (DMODEL / 8) + (k >> 3)) * 128 +
                           (n & 15) * 8 + (k & 7);
        dst[off] = f2bf(tile[tx][ty * 4 + j]);
    }
}

// ---------------------------------------------------------------------------
// Kernel 2: DEEP-PIPELINED 256x256 B^T GEMM, BK=64, 8 waves (2M x 4N),
// 160 KB LDS: As[3 slots] (A staged 2 K-tiles ahead) + Bs[2 slots], PK ops.
//   C[b][m][n] = sum_k A[b][m][k] * Bt[b][n][k]
// 1 K-tile per iteration, 4 phases (ph q=0..3 = one 2-row A quadrant each):
//   pre : READ_B(sb)  (8 ds_read_b128; B(kt), staged last iter)
//   ph1 : 4 A-reads q0 | STG B(kt+1)h0 -> Bs[sb^1] | lgkm0 | 16 MFMA
//   ph2 : q1           | STG B(kt+1)h1             | lgkm0 | 16 MFMA
//   ph3 : q2           | STG A(kt+2)h0 -> As[sa2]  | lgkm0 | 16 MFMA
//   ph4 : q3           | STG A(kt+2)h1 | vmcnt(4) | BAR | lgkm0 | 16 MFMA | BAR
// ONLY 2 barriers per K-tile.  vmcnt(4)@ph4: outstanding (oldest first) =
// A(kt+1)[4, prev ph3/4] + B(kt+1)[4, ph1/2] + A(kt+2)[4, ph3/4] = 12 ->
// drain to 4 lands A(kt+1) AND B(kt+1) (everything next iter reads), keeps
// A(kt+2) in flight.  A slack = 4-5 phases (~1000cy > HBM latency); A is the
// HBM-streamed operand in all three GEMMs (X / Q / P).
// Slot-safety ledger (all overwrites barrier-separated from last readers):
//   STG B(kt+1)->Bs[sb^1]@ph1/2: readers = READ_B @ iter kt-1, drained by
//     each wave's lgkm0(ph1,kt-1) < bar(ph4,kt-1); STG follows ENDBAR(kt-1).
//   STG A(kt+2)->As[(kt+2)%3 == (kt-1)%3]@ph3/4: readers = iter kt-1 ph1-4,
//     last drain lgkm0(ph4,kt-1) < MFMA(ph4,kt-1) < ENDBAR(kt-1) < STG.
// Visibility: all reads of iter kt follow bar(ph4,kt-1) which postdates every
// wave's vmcnt drain of A(kt)/B(kt).
// MODE 0: bf16 C in PK * scale. MODE 1: bf16 VT store (PK over [e][s]).
// MODE 2: f32 plain C * Linv[row].  MODE 3: merged QKV projection.
// BX=1: batch on blockIdx.x (XCD=batch).
// ---------------------------------------------------------------------------
#define STG_A(kt, sl, h)                                                          \
    do {                                                                          \
        const size_t g0 = (size_t)((h) * 8 + (tid >> 7)) * eldA +                 \
                          (size_t)(kt) * 1024 + (tid & 127) * 8;                  \
        gload16(Ab + g0, &As[sl][(h) * 8192 + tid * 8]);                          \
        gload16(Ab + g0 + 4 * eldA, &As[sl][(h) * 8192 + tid * 8 + 4096]);        \
    } while (0)
#define STG_B(kt, sl, h)                                                          \
    do {                                                                          \
        const size_t g0 = (size_t)((h) * 8 + (tid >> 7)) * eldB +                 \
                          (size_t)(kt) * 1024 + (tid & 127) * 8;                  \
        gload16(Bb + g0, &Bs[sl][(h) * 8192 + tid * 8]);                          \
        gload16(Bb + g0 + 4 * eldB, &Bs[sl][(h) * 8192 + tid * 8 + 4096]);        \
    } while (0)

#define READ_B(sl)                                                                \
    _Pragma("unroll") for (int j = 0; j < 4; j++) {                               \
        bfr[j][0] = *(const bf16x8*)&Bs[sl][(wc * 4 + j) * 1024 + lbase];         \
        bfr[j][1] = *(const bf16x8*)&Bs[sl][(wc * 4 + j) * 1024 + 512 + lbase];   \
    }

#define VM4 asm volatile("s_waitcnt vmcnt(4)" ::: "memory")
#define VM0 asm volatile("s_waitcnt vmcnt(0)" ::: "memory")
#define NOPW (void)0
#define NOST (void)0

#define MFMA_Q(q)                                                                 \
    __builtin_amdgcn_s_setprio(1);                                                \
    _Pragma("unroll") for (int j = 0; j < 4; j++) {                               \
        acc[2 * (q)][j] = MFMA16(a00, bfr[j][0], acc[2 * (q)][j]);                \
        acc[2 * (q)][j] = MFMA16(a01, bfr[j][1], acc[2 * (q)][j]);                \
        acc[2 * (q) + 1][j] = MFMA16(a10, bfr[j][0], acc[2 * (q) + 1][j]);        \
        acc[2 * (q) + 1][j] = MFMA16(a11, bfr[j][1], acc[2 * (q) + 1][j]);        \
    }                                                                             \
    __builtin_amdgcn_s_setprio(0);

#define PH_FREE(sl, q, STG)                                                       \
    do {                                                                          \
        const int ab = (wr * 8 + 2 * (q)) * 1024 + lbase;                         \
        bf16x8 a00 = *(const bf16x8*)&As[sl][ab];                                 \
        bf16x8 a01 = *(const bf16x8*)&As[sl][ab + 512];                           \
        bf16x8 a10 = *(const bf16x8*)&As[sl][ab + 1024];                          \
        bf16x8 a11 = *(const bf16x8*)&As[sl][ab + 1536];                          \
        STG;                                                                      \
        asm volatile("s_waitcnt lgkmcnt(0)" ::: "memory");                        \
        __builtin_amdgcn_sched_barrier(0);                                        \
        MFMA_Q(q)                                                                 \
    } while (0)

#define PH_SYNC(sl, q, STG, WAIT)                                                 \
    do {                                                                          \
        const int ab = (wr * 8 + 2 * (q)) * 1024 + lbase;                         \
        bf16x8 a00 = *(const bf16x8*)&As[sl][ab];                                 \
        bf16x8 a01 = *(const bf16x8*)&As[sl][ab + 512];                           \
        bf16x8 a10 = *(const bf16x8*)&As[sl][ab + 1024];                          \
        bf16x8 a11 = *(const bf16x8*)&As[sl][ab + 1536];                          \
        STG;                                                                      \
        WAIT;                                                                     \
        __builtin_amdgcn_s_barrier();                                             \
        asm volatile("s_waitcnt lgkmcnt(0)" ::: "memory");                        \
        __builtin_amdgcn_sched_barrier(0);                                        \
        MFMA_Q(q)                                                                 \
        __builtin_amdgcn_s_barrier();                                             \
    } while (0)

template <int MODE, int BX>
__global__ __launch_bounds__(512, 2) void gemm8p(const uint16_t* __restrict__ Ag,
                                                 const uint16_t* __restrict__ Bg,
                                                 void* __restrict__ Cg,
                                                 const float* __restrict__ Linv,
                                                 float scale, int lda, int ldb, int ldc,
                                                 int nk, size_t sA, size_t sB, size_t sC,
                                                 const uint16_t* __restrict__ A2,
                                                 const uint16_t* __restrict__ A3,
                                                 void* __restrict__ C2,
                                                 void* __restrict__ C3) {
    __shared__ __align__(16) uint16_t As[3][16384];   // 96 KB (3-slot rotation)
    __shared__ __align__(16) uint16_t Bs[2][16384];   // 64 KB -> 160 KB total
    const int bz = BX ? blockIdx.x : blockIdx.z;
    const int bm = BX ? blockIdx.y : blockIdx.x;
    const int bn = BX ? blockIdx.z : blockIdx.y;
    const int m0 = bm * 256, n0 = bn * 256;
    const uint16_t *Abase, *Bbase;
    if constexpr (MODE == 3) {
        // merged projection: bz = 0(Q) / 1(K) / 2(V); WT order in memory: K,V,Q
        Abase = (bz == 0) ? Ag : (bz == 1) ? A2 : A3;
        Bbase = Bg + ((bz == 0) ? 2 * sB : (bz == 1) ? (size_t)0 : sB);
    } else {
        Abase = Ag + (size_t)bz * sA;
        Bbase = Bg + (size_t)bz * sB;
    }
    const uint16_t* Ab = Abase + (size_t)m0 * lda;  // PK panel base
    const uint16_t* Bb = Bbase + (size_t)n0 * ldb;
    const int tid = threadIdx.x, lane = tid & 63;
    const int wid = tid >> 6, wr = wid >> 2, wc = wid & 3;
    const int lr = lane & 15, lg = lane >> 4;
    const int lbase = lg * 128 + lr * 8;
    const size_t eldA = (size_t)lda * 16, eldB = (size_t)ldb * 16;

    f32x4 acc[8][4] = {};
    bf16x8 bfr[4][2];
    // prologue: A(0)->As[0], B(0)->Bs[0], A(1)->As[1]; vmcnt(4) drains
    // A(0)+B(0), leaves A(1) in flight.
    STG_A(0, 0, 0); STG_A(0, 0, 1);
    STG_B(0, 0, 0); STG_B(0, 0, 1);
    STG_A(1, 1, 0); STG_A(1, 1, 1);
    VM4;
    __builtin_amdgcn_s_barrier();
    int sa = 0, sa2 = 2, sb = 0;   // sa=kt%3, sa2=(kt+2)%3, sb=kt&1
    for (int kt = 0; kt < nk - 2; ++kt) {
        READ_B(sb);
        PH_FREE(sa, 0, STG_B(kt + 1, sb ^ 1, 0));
        PH_FREE(sa, 1, STG_B(kt + 1, sb ^ 1, 1));
        PH_FREE(sa, 2, STG_A(kt + 2, sa2, 0));
        PH_SYNC(sa, 3, STG_A(kt + 2, sa2, 1), VM4);
        sa = (sa == 2) ? 0 : sa + 1;
        sa2 = (sa2 == 2) ? 0 : sa2 + 1;
        sb ^= 1;
    }
    // kt = nk-2: stage last B only; drain everything for the final tile.
    READ_B(sb);
    PH_FREE(sa, 0, STG_B(nk - 1, sb ^ 1, 0));
    PH_FREE(sa, 1, STG_B(nk - 1, sb ^ 1, 1));
    PH_FREE(sa, 2, NOST);
    PH_SYNC(sa, 3, NOST, VM0);
    sa = (sa == 2) ? 0 : sa + 1;
    sb ^= 1;
    // kt = nk-1: no staging, no vm wait.
    READ_B(sb);
    PH_FREE(sa, 0, NOST);
    PH_FREE(sa, 1, NOST);
    PH_FREE(sa, 2, NOST);
    PH_SYNC(sa, 3, NOST, NOPW);

    if constexpr (MODE == 0) {
        uint16_t* C = (uint16_t*)Cg + (size_t)bz * sC;
#pragma unroll
        for (int i = 0; i < 8; i++) {
            const int gm = m0 + wr * 128 + i * 16 + lg * 4;   // gm&15 == lg*4
            const size_t pbase = (size_t)(gm >> 4) * (ldc / 8);
#pragma unroll
            for (int j = 0; j < 4; j++) {
                const int gn = n0 + wc * 64 + j * 16 + lr;
                const size_t off = (pbase + (gn >> 3)) * 128 + (gn & 7);
#pragma unroll
                for (int r = 0; r < 4; r++)
                    C[off + (lg * 4 + r) * 8] = f2bf(acc[i][j][r] * scale);
            }
        }
    } else if constexpr (MODE == 1) {
        uint16_t* C = (uint16_t*)Cg;
#pragma unroll
        for (int i = 0; i < 8; i++) {
            const int gm = m0 + wr * 128 + i * 16 + lg * 4;  // global m = b*SEQ + s
            const int bb = gm / SEQ;                         // uniform per block
            const int s0 = gm - bb * SEQ;                    // s0&7 in {0,4}
            uint16_t* Cb = C + (size_t)bb * DMODEL * SEQ;
#pragma unroll
            for (int j = 0; j < 4; j++) {
                const int e = n0 + wc * 64 + j * 16 + lr;
                const size_t off = ((size_t)(e >> 4) * (SEQ / 8) + (s0 >> 3)) * 128 +
                                   (e & 15) * 8 + (s0 & 7);
                u32x2 v = {pk2(acc[i][j][0], acc[i][j][1]), pk2(acc[i][j][2], acc[i][j][3])};
                *(u32x2*)&Cb[off] = v;
            }
        }
    } else if constexpr (MODE == 2) {
        float* C = (float*)Cg + (size_t)bz * sC;
        const float* LB = Linv + bz * SEQ;
#pragma unroll
        for (int i = 0; i < 8; i++) {
            const int gm = m0 + wr * 128 + i * 16 + lg * 4;
            const f32x4 lv = *(const f32x4*)&LB[gm];
#pragma unroll
            for (int j = 0; j < 4; j++) {
                const int gn = n0 + wc * 64 + j * 16 + lr;
#pragma unroll
                for (int r = 0; r < 4; r++)
                    C[(size_t)(gm + r) * ldc + gn] = acc[i][j][r] * lv[r];
            }
        }
    } else {  // MODE 3: merged projection epilogue
        if (bz < 2) {
            uint16_t* C = (uint16_t*)(bz == 0 ? Cg : C2);
            const float sc = bz == 0 ? scale : 1.0f;
#pragma unroll
            for (int i = 0; i < 8; i++) {
                const int gm = m0 + wr * 128 + i * 16 + lg * 4;
                const size_t pbase = (size_t)(gm >> 4) * (ldc / 8);
#pragma unroll
                for (int j = 0; j < 4; j++) {
                    const int gn = n0 + wc * 64 + j * 16 + lr;
                    const size_t off = (pbase + (gn >> 3)) * 128 + (gn & 7);
#pragma unroll
                    for (int r = 0; r < 4; r++)
                        C[off + (lg * 4 + r) * 8] = f2bf(acc[i][j][r] * sc);
                }
            }
        } else {
            uint16_t* C = (uint16_t*)C3;
#pragma unroll
            for (int i = 0; i < 8; i++) {
                const int gm = m0 + wr * 128 + i * 16 + lg * 4;
                const int bb = gm / SEQ;
                const int s0 = gm - bb * SEQ;
                uint16_t* Cb = C + (size_t)bb * DMODEL * SEQ;
#pragma unroll
                for (int j = 0; j < 4; j++) {
                    const int e = n0 + wc * 64 + j * 16 + lr;
                    const size_t off = ((size_t)(e >> 4) * (SEQ / 8) + (s0 >> 3)) * 128 +
                                       (e & 15) * 8 + (s0 & 7);
                    u32x2 v = {pk2(acc[i][j][0], acc[i][j][1]),
                               pk2(acc[i][j][2], acc[i][j][3])};
                    *(u32x2*)&Cb[off] = v;
                }
            }
        }
    }
}

// ---------------------------------------------------------------------------
// Kernel 3: row softmax on PK-layout S, in place.  One block per 16-row panel
// (contiguous 32KB).  Thread t owns row t&15, k-slots (t>>4)+16u, u=0..15.
// ---------------------------------------------------------------------------
__global__ __launch_bounds__(256) void softmax_pk(uint16_t* __restrict__ S,
                                                  float* __restrict__ Linv) {
    const size_t panel = blockIdx.x;
    uint16_t* sp = S + panel * (size_t)(16 * SEQ);
    const int t = threadIdx.x, lane = t & 63, w = t >> 6;
    const int r15 = t & 15, ksl = t >> 4;
    __shared__ float rm[4][16], rs[4][16];
    u32x4 raw[16];
    float mx = -3.0e38f;
#pragma unroll
    for (int u = 0; u < 16; u++) {
        raw[u] = *(const u32x4*)&sp[(ksl + u * 16) * 128 + r15 * 8];
#pragma unroll
        for (int j = 0; j < 4; j++) {
            mx = fmaxf(mx, __builtin_bit_cast(float, raw[u][j] << 16));
            mx = fmaxf(mx, __builtin_bit_cast(float, raw[u][j] & 0xffff0000u));
        }
    }
    mx = fmaxf(mx, __shfl_xor(mx, 16));
    mx = fmaxf(mx, __shfl_xor(mx, 32));
    if (lane < 16) rm[w][lane] = mx;
    __syncthreads();
    const float m = fmaxf(fmaxf(rm[0][r15], rm[1][r15]), fmaxf(rm[2][r15], rm[3][r15]));
    float sum = 0.0f;
#pragma unroll
    for (int u = 0; u < 16; u++) {
#pragma unroll
        for (int j = 0; j < 4; j++) {
            float lo = __expf(__builtin_bit_cast(float, raw[u][j] << 16) - m);
            float hi = __expf(__builtin_bit_cast(float, raw[u][j] & 0xffff0000u) - m);
            sum += lo + hi;
            raw[u][j] = pk2(lo, hi);
        }
    }
    sum += __shfl_xor(sum, 16);
    sum += __shfl_xor(sum, 32);
    if (lane < 16) rs[w][lane] = sum;
    __syncthreads();
    const float tot = rs[0][r15] + rs[1][r15] + rs[2][r15] + rs[3][r15];
#pragma unroll
    for (int u = 0; u < 16; u++)
        *(u32x4*)&sp[(ksl + u * 16) * 128 + r15 * 8] = raw[u];
    if (w == 0 && lane < 16) Linv[panel * 16 + lane] = 1.0f / tot;
}

// ---------------------------------------------------------------------------
// Buffer plan (aliasing-audited):
//   ws:  Qbf [0, 33.5M)  Kbf [33.5M, 67.1M)  VTb [67.1M, 100.7M)
//        WT  [100.7M, 106.95M)  Linv [106.95M, ~107M)
//        S/P [107,020,288 .. 174,129,152)
//   X casts (all DISJOINT, dead before their region is re-written):
//        XqB = d_out[0 .. 32M)            (PV writes all of d_out at the end)
//        XkB = S + 0       [107,020,288)  (scores writes S after proj done)
//        XvB = S + 33.5MB  [140,574,720)
//   Temporal chain: cast3 -> proj(reads X*, writes Q/K/VT) -> scores(clobbers
//   XkB/XvB) -> softmax -> PV(clobbers XqB, writes full out).
// ---------------------------------------------------------------------------
extern "C" void kernel_launch(void* const* d_in, const int* in_sizes, int n_in,
                              void* d_out, int out_size, void* d_ws, size_t ws_size,
                              hipStream_t stream) {
    const float* Xk = (const float*)d_in[0];
    const float* Xv = (const float*)d_in[1];
    const float* Xq = (const float*)d_in[2];
    const float* Wk = (const float*)d_in[3];
    const float* Wv = (const float*)d_in[4];
    const float* Wq = (const float*)d_in[5];
    float* out = (float*)d_out;
    char* ws = (char*)d_ws;
    uint16_t* Qbf = (uint16_t*)(ws);
    uint16_t* Kbf = (uint16_t*)(ws + (size_t)33554432);
    uint16_t* VTb = (uint16_t*)(ws + (size_t)67108864);
    uint16_t* WT  = (uint16_t*)(ws + (size_t)100663296);
    float*    Linv= (float*)(ws + (size_t)106954752);
    uint16_t* Sb  = (uint16_t*)(ws + (size_t)107020288);
    uint16_t* XqB = (uint16_t*)d_out;                        // 32 MB of 64 MB out
    uint16_t* XkB = Sb;                                      // S + 0
    uint16_t* XvB = (uint16_t*)(ws + (size_t)140574720);     // S + 32 MB

    wt_cast_kernel<<<dim3(32, 32, 3), dim3(32, 8), 0, stream>>>(Wk, Wv, Wq, WT);
    // all three input casts in one dispatch (disjoint destinations)
    cast3_bf16_pk<<<dim3(8192, 3), 256, 0, stream>>>(Xq, Xk, Xv, XqB, XkB, XvB);
    // merged Q/K/V projection: z=0 Q (scale 1/32), z=1 K, z=2 V (VT store)
    gemm8p<3, 0><<<dim3(64, 4, 3), 512, 0, stream>>>(
        XqB, WT, (void*)Qbf, nullptr, 0.03125f,
        DMODEL, DMODEL, DMODEL, DMODEL / 64,
        0, (size_t)1048576 /*WT stride*/, 0,
        XkB, XvB, (void*)Kbf, (void*)VTb);
    // scores: S[b][q][k] = Qhat[b] . K[b]^T  (bf16 PK store), XCD = batch
    gemm8p<0, 1><<<dim3(8, 8, 8), 512, 0, stream>>>(
        Qbf, Kbf, (void*)Sb, nullptr, 1.0f,
        DMODEL, DMODEL, SEQ, DMODEL / 64,
        (size_t)SEQ * DMODEL, (size_t)SEQ * DMODEL, (size_t)SEQ * SEQ,
        nullptr, nullptr, nullptr, nullptr);
    // in-place row softmax -> P, Linv
    softmax_pk<<<dim3(BATCH * SEQ / 16), 256, 0, stream>>>(Sb, Linv);
    // Z[b][q][e] = (P[b] . V[b]) * Linv  (f32 plain store)
    gemm8p<2, 1><<<dim3(8, 8, 4), 512, 0, stream>>>(
        Sb, VTb, (void*)out, Linv, 1.0f,
        SEQ, SEQ, DMODEL, SEQ / 64,
        (size_t)SEQ * SEQ, (size_t)DMODEL * SEQ, (size_t)SEQ * DMODEL,
        nullptr, nullptr, nullptr, nullptr);
}